// Round 1
// baseline (390.667 us; speedup 1.0000x reference)
//
#include <hip/hip_runtime.h>

// Exact Gaussian lattice filter: out = (W - I) @ U, W_ij = exp(-0.5*max(d2,0))
// N=8192 rows, D=5 feature dims, C=21 channels.
//
// Compute-bound fp32 VALU kernel. Per (i,j): x = a_i + a_j + f_i . f'_j
// where f'_j = log2(e)*f_j, a = -0.5*log2(e)*||f||^2, then w = 2^min(x,0),
// acc[c] += w * U_j[c].

#define NN 8192
#define CC 21
#define DD 5
#define BLOCK 256
#define IT 2                 // i-rows per thread
#define TI (BLOCK * IT)      // 512 i-rows per block
#define NI (NN / TI)         // 16 i-tiles
#define JC 32                // j-chunks
#define JCHUNK (NN / JC)     // 256 j per chunk (== BLOCK)

__global__ __launch_bounds__(BLOCK, 2)
void lattice_gauss_main(const float* __restrict__ U,
                        const float* __restrict__ ref,
                        float* __restrict__ out) {
    __shared__ float4 sF[JCHUNK * 2];  // per j: {L*f0..L*f3}, {L*f4, a_j, 0, 0}
    __shared__ float4 sU[JCHUNK * 6];  // per j: U[0..20] padded to 24 floats

    const int t  = threadIdx.x;
    const int ib = blockIdx.x;
    const int jc = blockIdx.y;
    const int jbase = jc * JCHUNK;

    // ---- stage this block's j-chunk into LDS (one j per thread) ----
    {
        const int j = jbase + t;
        const float* fj = ref + (size_t)j * DD;
        const float L = 1.4426950408889634f;          // log2(e)
        float f0 = fj[0], f1 = fj[1], f2 = fj[2], f3 = fj[3], f4 = fj[4];
        float sq = f0*f0 + f1*f1 + f2*f2 + f3*f3 + f4*f4;
        sF[t * 2 + 0] = make_float4(L * f0, L * f1, L * f2, L * f3);
        sF[t * 2 + 1] = make_float4(L * f4, -0.5f * L * sq, 0.f, 0.f);

        const float* uj = U + (size_t)j * CC;
        float* su = (float*)&sU[t * 6];
        #pragma unroll
        for (int c = 0; c < CC; ++c) su[c] = uj[c];
        su[21] = 0.f; su[22] = 0.f; su[23] = 0.f;
    }
    __syncthreads();

    // ---- per-thread i-row state ----
    float fi[IT][DD];
    float ai[IT];
    float acc[IT][CC];
    #pragma unroll
    for (int r = 0; r < IT; ++r) {
        const int i = ib * TI + r * BLOCK + t;
        const float* f = ref + (size_t)i * DD;
        #pragma unroll
        for (int d = 0; d < DD; ++d) fi[r][d] = f[d];
        float sq = 0.f;
        #pragma unroll
        for (int d = 0; d < DD; ++d) sq = fmaf(fi[r][d], fi[r][d], sq);
        ai[r] = -0.7213475204444817f * sq;            // -0.5*log2(e)*||f_i||^2
        if (jc == 0) {
            const float* ui = U + (size_t)i * CC;
            #pragma unroll
            for (int c = 0; c < CC; ++c) acc[r][c] = -ui[c];
        } else {
            #pragma unroll
            for (int c = 0; c < CC; ++c) acc[r][c] = 0.f;
        }
    }

    // ---- main loop over the j-chunk (all LDS reads are wave-uniform broadcasts) ----
    #pragma unroll 2
    for (int j = 0; j < JCHUNK; ++j) {
        const float4 fA = sF[j * 2 + 0];
        const float4 fB = sF[j * 2 + 1];
        const float4 u0 = sU[j * 6 + 0];
        const float4 u1 = sU[j * 6 + 1];
        const float4 u2 = sU[j * 6 + 2];
        const float4 u3 = sU[j * 6 + 3];
        const float4 u4 = sU[j * 6 + 4];
        const float4 u5 = sU[j * 6 + 5];
        float us[24];
        *(float4*)&us[0]  = u0;  *(float4*)&us[4]  = u1;
        *(float4*)&us[8]  = u2;  *(float4*)&us[12] = u3;
        *(float4*)&us[16] = u4;  *(float4*)&us[20] = u5;

        #pragma unroll
        for (int r = 0; r < IT; ++r) {
            float x = ai[r] + fB.y;
            x = fmaf(fi[r][0], fA.x, x);
            x = fmaf(fi[r][1], fA.y, x);
            x = fmaf(fi[r][2], fA.z, x);
            x = fmaf(fi[r][3], fA.w, x);
            x = fmaf(fi[r][4], fB.x, x);
            x = fminf(x, 0.f);                        // max(d2,0) clamp
            const float w = __builtin_amdgcn_exp2f(x);
            #pragma unroll
            for (int c = 0; c < CC; ++c)
                acc[r][c] = fmaf(w, us[c], acc[r][c]);
        }
    }

    // ---- accumulate partials into out ----
    #pragma unroll
    for (int r = 0; r < IT; ++r) {
        const int i = ib * TI + r * BLOCK + t;
        float* o = out + (size_t)i * CC;
        #pragma unroll
        for (int c = 0; c < CC; ++c)
            unsafeAtomicAdd(&o[c], acc[r][c]);
    }
}

extern "C" void kernel_launch(void* const* d_in, const int* in_sizes, int n_in,
                              void* d_out, int out_size, void* d_ws, size_t ws_size,
                              hipStream_t stream) {
    const float* U   = (const float*)d_in[0];
    const float* ref = (const float*)d_in[1];
    float* out = (float*)d_out;

    hipMemsetAsync(out, 0, (size_t)out_size * sizeof(float), stream);

    dim3 grid(NI, JC);
    lattice_gauss_main<<<grid, BLOCK, 0, stream>>>(U, ref, out);
}

// Round 2
// 71.746 us; speedup vs baseline: 5.4451x; 5.4451x over previous
//
#include <hip/hip_runtime.h>

// Exact Gaussian lattice filter: out = (W - I) @ U, W_ij = exp(-0.5*max(d2,0))
// N=8192 rows, D=5 feature dims, C=21 channels.
//
// VALU-bound fp32 kernel. Per (i,j): x = a_i + a_j + f_i . f'_j  where
// f'_j = log2(e)*f_j, a = -0.5*log2(e)*||f||^2; w = 2^min(x,0);
// acc[c] += w * U_j[c].
//
// R2 changes vs R1 (which was latency-bound: 390us, VALUBusy 12%, occ 15.5%):
//  - grid 512 -> 1024 blocks (JCHUNK 256->128, JC 32->64): ~6 blocks/CU,
//    24 waves/CU with __launch_bounds__(256,6).
//  - per-j LDS packed to 7 float4 (U[20] in fB.z): 14 KiB staging.
//  - coalesced atomic epilogue via LDS transpose (R1 had 172MB of
//    uncoalesced lane-atomic write traffic).

#define NN 8192
#define CC 21
#define DD 5
#define BLOCK 256
#define IT 2                  // i-rows per thread
#define TI (BLOCK * IT)       // 512 rows per block
#define NI (NN / TI)          // 16 i-tiles
#define JC 64                 // j-chunks
#define JCHUNK (NN / JC)      // 128 j per chunk

__global__ __launch_bounds__(BLOCK, 6)
void lattice_gauss_main(const float* __restrict__ U,
                        const float* __restrict__ ref,
                        float* __restrict__ out) {
    // staging: per j, 7 float4 = {L*f0..3}, {L*f4, a_j, U20, 0}, U[0..19]
    // F: JCHUNK*2 float4 (4096 B), Uv: JCHUNK*5 float4 (10240 B) = 14336 B.
    // epilogue reuses the same LDS as 2688 floats (10752 B).
    __shared__ __align__(16) char smem_raw[14336];
    float4* sF  = (float4*)smem_raw;
    float4* sUv = (float4*)(smem_raw + 4096);
    float*  red = (float*)smem_raw;

    const int t  = threadIdx.x;
    const int ib = blockIdx.x;
    const int jc = blockIdx.y;
    const int jbase = jc * JCHUNK;
    const float L = 1.4426950408889634f;   // log2(e)

    // ---- stage j-chunk: thread pair (j = t>>1, half = t&1) ----
    {
        const int j  = t >> 1;
        const int jg = jbase + j;
        if ((t & 1) == 0) {
            const float* fj = ref + (size_t)jg * DD;
            float f0 = fj[0], f1 = fj[1], f2 = fj[2], f3 = fj[3], f4 = fj[4];
            float sq = f0*f0 + f1*f1 + f2*f2 + f3*f3 + f4*f4;
            sF[j*2+0] = make_float4(L*f0, L*f1, L*f2, L*f3);
            sF[j*2+1] = make_float4(L*f4, -0.5f*L*sq, U[(size_t)jg*CC + 20], 0.f);
        } else {
            const float* uj = U + (size_t)jg * CC;
            float* su = (float*)&sUv[j*5];
            #pragma unroll
            for (int c = 0; c < 20; ++c) su[c] = uj[c];
        }
    }

    // ---- per-thread i-row state (2 rows: t and t+256) ----
    float fi[IT][DD];
    float ai[IT];
    float acc[IT][CC];
    #pragma unroll
    for (int r = 0; r < IT; ++r) {
        const int i = ib * TI + r * BLOCK + t;
        const float* f = ref + (size_t)i * DD;
        #pragma unroll
        for (int d = 0; d < DD; ++d) fi[r][d] = f[d];
        float sq = 0.f;
        #pragma unroll
        for (int d = 0; d < DD; ++d) sq = fmaf(fi[r][d], fi[r][d], sq);
        ai[r] = -0.7213475204444817f * sq;   // -0.5*log2(e)*||f_i||^2
        if (jc == 0) {
            const float* ui = U + (size_t)i * CC;
            #pragma unroll
            for (int c = 0; c < CC; ++c) acc[r][c] = -ui[c];
        } else {
            #pragma unroll
            for (int c = 0; c < CC; ++c) acc[r][c] = 0.f;
        }
    }
    __syncthreads();

    // ---- main loop: all LDS reads are wave-uniform broadcasts ----
    #pragma unroll 2
    for (int j = 0; j < JCHUNK; ++j) {
        const float4 fA = sF[j*2+0];
        const float4 fB = sF[j*2+1];
        float w[IT];
        #pragma unroll
        for (int r = 0; r < IT; ++r) {
            float x = ai[r] + fB.y;
            x = fmaf(fi[r][0], fA.x, x);
            x = fmaf(fi[r][1], fA.y, x);
            x = fmaf(fi[r][2], fA.z, x);
            x = fmaf(fi[r][3], fA.w, x);
            x = fmaf(fi[r][4], fB.x, x);
            x = fminf(x, 0.f);
            w[r] = __builtin_amdgcn_exp2f(x);
        }
        const float4 u0 = sUv[j*5+0];
        const float4 u1 = sUv[j*5+1];
        const float4 u2 = sUv[j*5+2];
        const float4 u3 = sUv[j*5+3];
        const float4 u4 = sUv[j*5+4];
        #pragma unroll
        for (int r = 0; r < IT; ++r) {
            acc[r][0]  = fmaf(w[r], u0.x, acc[r][0]);
            acc[r][1]  = fmaf(w[r], u0.y, acc[r][1]);
            acc[r][2]  = fmaf(w[r], u0.z, acc[r][2]);
            acc[r][3]  = fmaf(w[r], u0.w, acc[r][3]);
            acc[r][4]  = fmaf(w[r], u1.x, acc[r][4]);
            acc[r][5]  = fmaf(w[r], u1.y, acc[r][5]);
            acc[r][6]  = fmaf(w[r], u1.z, acc[r][6]);
            acc[r][7]  = fmaf(w[r], u1.w, acc[r][7]);
            acc[r][8]  = fmaf(w[r], u2.x, acc[r][8]);
            acc[r][9]  = fmaf(w[r], u2.y, acc[r][9]);
            acc[r][10] = fmaf(w[r], u2.z, acc[r][10]);
            acc[r][11] = fmaf(w[r], u2.w, acc[r][11]);
            acc[r][12] = fmaf(w[r], u3.x, acc[r][12]);
            acc[r][13] = fmaf(w[r], u3.y, acc[r][13]);
            acc[r][14] = fmaf(w[r], u3.z, acc[r][14]);
            acc[r][15] = fmaf(w[r], u3.w, acc[r][15]);
            acc[r][16] = fmaf(w[r], u4.x, acc[r][16]);
            acc[r][17] = fmaf(w[r], u4.y, acc[r][17]);
            acc[r][18] = fmaf(w[r], u4.z, acc[r][18]);
            acc[r][19] = fmaf(w[r], u4.w, acc[r][19]);
            acc[r][20] = fmaf(w[r], fB.z, acc[r][20]);
        }
    }

    // ---- coalesced atomic epilogue: 4 quarters of 128 rows via LDS ----
    // quarter q: acc half a = q>>1, thread range (q&1)*128 .. +128
    for (int q = 0; q < 4; ++q) {
        __syncthreads();
        const int a = q >> 1;
        if ((t >> 7) == (q & 1)) {
            const int rl = t & 127;
            #pragma unroll
            for (int c = 0; c < CC; ++c) red[rl * CC + c] = acc[a][c];
        }
        __syncthreads();
        const size_t obase = (size_t)(ib * TI + a * BLOCK + (q & 1) * 128) * CC;
        #pragma unroll
        for (int k = 0; k <= 10; ++k) {
            const int idx = k * BLOCK + t;
            if (idx < 128 * CC)
                unsafeAtomicAdd(&out[obase + idx], red[idx]);
        }
    }
}

extern "C" void kernel_launch(void* const* d_in, const int* in_sizes, int n_in,
                              void* d_out, int out_size, void* d_ws, size_t ws_size,
                              hipStream_t stream) {
    const float* U   = (const float*)d_in[0];
    const float* ref = (const float*)d_in[1];
    float* out = (float*)d_out;

    hipMemsetAsync(out, 0, (size_t)out_size * sizeof(float), stream);

    dim3 grid(NI, JC);
    lattice_gauss_main<<<grid, BLOCK, 0, stream>>>(U, ref, out);
}

// Round 5
// 47.527 us; speedup vs baseline: 8.2199x; 1.5096x over previous
//
#include <hip/hip_runtime.h>

// Exact Gaussian lattice filter: out = (W - I) @ U, W_ij = exp(-0.5*max(d2,0))
// N=8192, D=5 features, C=21 channels.
//
// R5: MFMA hybrid, maximally-vanilla variant to discriminate R3/R4's failure.
//  - 32x32x16 bf16 MFMA (C/D layout double-verified m74/m101:
//    col=lane&31, row=(reg&3)+8*(reg>>2)+4*(lane>>5))
//  - no inline asm: bf16 RNE pack via integer ops
//  - no unaligned vector casts: fragments built as u32x4
//  - plain f_j LDS layout (per-e reads are 2-way broadcasts -> free)
// Exponent exact fp32: x = ai + aj + fi . (log2e * fj); w = 2^min(x,0).
// One 32-row i-tile per wave; 16 js per MFMA step; B packed in LDS per window.

#define NN 8192
#define CC 21
#define DD 5
#define BLOCK 256
#define IBLK 128                // 4 waves x 32 rows
#define NIB (NN / IBLK)         // 64
#define JSPLIT 16
#define JCHUNK (NN / JSPLIT)    // 512
#define JWIN 256
#define NWIN (JCHUNK / JWIN)    // 2
#define JSTEP 16
#define NSTEP (JWIN / JSTEP)    // 16

typedef __attribute__((ext_vector_type(8)))  short    bf16x8;
typedef __attribute__((ext_vector_type(16))) float    f32x16;
typedef __attribute__((ext_vector_type(4)))  unsigned u32x4;

__device__ __forceinline__ unsigned f32_to_bf16_rne(float x) {
    unsigned u = __builtin_bit_cast(unsigned, x);
    return (u + 0x7fffu + ((u >> 16) & 1u)) >> 16;   // round-nearest-even
}

__global__ __launch_bounds__(BLOCK, 4)
void lattice_gauss_mfma32(const float* __restrict__ U,
                          const float* __restrict__ ref,
                          float* __restrict__ out) {
    // LDS: [0,8192) f-staging, 32B per j: {L*f0..L*f3},{L*f4, a_j, pad, pad}
    //      [8192, 24576) B-fragments: 16B per (step s, frag-lane ln) at (s*64+ln)*16
    __shared__ __align__(16) char smem[JWIN * 32 + NSTEP * 64 * 16];
    char* sFm = smem;
    char* sB  = smem + JWIN * 32;

    const int t    = threadIdx.x;
    const int lane = t & 63;
    const int wv   = t >> 6;           // wave 0..3
    const int h    = lane >> 5;        // k-half 0..1
    const int m    = lane & 31;        // A row / D col (channel)
    const int iblock = blockIdx.x;
    const int jc     = blockIdx.y;
    const float L  = 1.4426950408889634f;    // log2(e)
    const float NH = -0.7213475204444817f;   // -0.5*log2(e)

    const int ibase = iblock * IBLK + wv * 32;

    // ---- per-lane i-row features (row m of this wave's 32-row tile) ----
    const float* fiP = ref + (size_t)(ibase + m) * DD;
    const float fi0 = fiP[0], fi1 = fiP[1], fi2 = fiP[2], fi3 = fiP[3], fi4 = fiP[4];
    const float ai = NH * (fi0*fi0 + fi1*fi1 + fi2*fi2 + fi3*fi3 + fi4*fi4);

    // ---- accumulator: D[row][col=m]; fold -U at jc==0 ----
    f32x16 acc;
    #pragma unroll
    for (int r = 0; r < 16; ++r) acc[r] = 0.f;
    if (jc == 0 && m < CC) {
        #pragma unroll
        for (int r = 0; r < 16; ++r) {
            const int row = (r & 3) + 8 * (r >> 2) + 4 * h;
            acc[r] = -U[(size_t)(ibase + row) * CC + m];
        }
    }

    for (int win = 0; win < NWIN; ++win) {
        const int jwbase = jc * JCHUNK + win * JWIN;
        __syncthreads();   // protect smem reuse across windows

        // ---- stage f_j: thread t -> j = t ----
        {
            const int j = t;
            const float* fj = ref + (size_t)(jwbase + j) * DD;
            const float f0 = fj[0], f1 = fj[1], f2 = fj[2], f3 = fj[3], f4 = fj[4];
            const float sq = f0*f0 + f1*f1 + f2*f2 + f3*f3 + f4*f4;
            char* pw = sFm + j * 32;
            *(float4*)pw        = make_float4(L*f0, L*f1, L*f2, L*f3);
            *(float2*)(pw + 16) = make_float2(L*f4, NH * sq);
        }

        // ---- pack B-fragments: slot q = s*64 + ln, 4 slots per thread ----
        // B[k][n]: n = ln&31 (channel), k-slot = (ln>>5)*8 + e -> j = jwbase + s*16 + k-slot
        for (int q = t; q < NSTEP * 64; q += BLOCK) {
            const int s_ = q >> 6;
            const int ln = q & 63;
            const int c  = ln & 31;
            const int jb = jwbase + s_ * JSTEP + (ln >> 5) * 8;
            unsigned pk[4];
            if (c < CC) {
                #pragma unroll
                for (int p = 0; p < 4; ++p) {
                    const unsigned lo = f32_to_bf16_rne(U[(size_t)(jb + 2*p)     * CC + c]);
                    const unsigned hi = f32_to_bf16_rne(U[(size_t)(jb + 2*p + 1) * CC + c]);
                    pk[p] = lo | (hi << 16);
                }
            } else {
                pk[0] = pk[1] = pk[2] = pk[3] = 0u;
            }
            u32x4 v = {pk[0], pk[1], pk[2], pk[3]};
            *(u32x4*)(sB + (size_t)q * 16) = v;
        }
        __syncthreads();

        // ---- compute: 16 steps of 16 js ----
        for (int s = 0; s < NSTEP; ++s) {
            const u32x4 braw = *(const u32x4*)(sB + ((s * 64 + lane) * 16));
            const bf16x8 bfrag = __builtin_bit_cast(bf16x8, braw);

            unsigned av[8];
            #pragma unroll
            for (int e = 0; e < 8; ++e) {
                const char* pr = sFm + (s * JSTEP + h * 8 + e) * 32;
                const float4 fA = *(const float4*)pr;
                const float2 fB = *(const float2*)(pr + 16);
                float x = ai + fB.y;
                x = fmaf(fi0, fA.x, x);
                x = fmaf(fi1, fA.y, x);
                x = fmaf(fi2, fA.z, x);
                x = fmaf(fi3, fA.w, x);
                x = fmaf(fi4, fB.x, x);
                x = fminf(x, 0.f);
                av[e] = f32_to_bf16_rne(__builtin_amdgcn_exp2f(x));
            }
            u32x4 araw = {av[0] | (av[1] << 16),
                          av[2] | (av[3] << 16),
                          av[4] | (av[5] << 16),
                          av[6] | (av[7] << 16)};
            const bf16x8 afrag = __builtin_bit_cast(bf16x8, araw);

            acc = __builtin_amdgcn_mfma_f32_32x32x16_bf16(afrag, bfrag, acc, 0, 0, 0);
        }
    }

    // ---- epilogue: D col = m (channel), row = (r&3) + 8*(r>>2) + 4*h ----
    if (m < CC) {
        #pragma unroll
        for (int r = 0; r < 16; ++r) {
            const int row = (r & 3) + 8 * (r >> 2) + 4 * h;
            unsafeAtomicAdd(&out[(size_t)(ibase + row) * CC + m], acc[r]);
        }
    }
}

extern "C" void kernel_launch(void* const* d_in, const int* in_sizes, int n_in,
                              void* d_out, int out_size, void* d_ws, size_t ws_size,
                              hipStream_t stream) {
    const float* U   = (const float*)d_in[0];
    const float* ref = (const float*)d_in[1];
    float* out = (float*)d_out;

    hipMemsetAsync(out, 0, (size_t)out_size * sizeof(float), stream);

    dim3 grid(NIB, JSPLIT);
    lattice_gauss_mfma32<<<grid, BLOCK, 0, stream>>>(U, ref, out);
}